// Round 3
// baseline (620.025 us; speedup 1.0000x reference)
//
#include <hip/hip_runtime.h>

#define FCOUNT 786432   // 12 * 256 * 256
#define SEGBITS 12
#define SEG 4096        // facets per segment
#define NSEG 192        // FCOUNT / SEG
#define JBITS 18
#define JMASK ((1 << JBITS) - 1)
#define ITEMS 16
#define BLK 256
#define CHUNKSZ (BLK * ITEMS)   // 4096 items per block

struct MsLds {
    int hist[NSEG];
    int lstart[NSEG];
    int cursor[NSEG];
    int gbase[NSEG];
    int wsum[BLK / 64];
    int staged[CHUNKSZ];        // 16 KB
};

// Block-level multisplit: stage entries ordered by segment in LDS, then copy
// per-segment runs to the global buckets (near-coalesced writes).
// f[i] < 0 marks invalid/out-of-range items. j is recomputed from load layout.
__device__ __forceinline__ void multisplit(MsLds& L, const int (&f)[ITEMS],
                                           int jb, int b, int* __restrict__ cnt,
                                           int* __restrict__ bucket, int cap,
                                           int tid) {
    for (int t = tid; t < NSEG; t += BLK) { L.hist[t] = 0; L.cursor[t] = 0; }
    __syncthreads();
    #pragma unroll
    for (int i = 0; i < ITEMS; i++)
        if (f[i] >= 0) atomicAdd(&L.hist[f[i] >> SEGBITS], 1);
    __syncthreads();
    // exclusive scan hist -> lstart (wave shfl scan + cross-wave offsets)
    int v = (tid < NSEG) ? L.hist[tid] : 0;
    int lane = tid & 63, w = tid >> 6;
    #pragma unroll
    for (int d = 1; d < 64; d <<= 1) {
        int u = __shfl_up(v, d, 64);
        if (lane >= d) v += u;
    }
    if (lane == 63) L.wsum[w] = v;
    __syncthreads();
    int add = 0;
    for (int ww = 0; ww < w; ww++) add += L.wsum[ww];
    v += add;
    if (tid < NSEG) L.lstart[tid] = v - L.hist[tid];
    for (int t = tid; t < NSEG; t += BLK)
        L.gbase[t] = L.hist[t] ? atomicAdd(&cnt[b * NSEG + t], L.hist[t]) : 0;
    __syncthreads();
    #pragma unroll
    for (int i = 0; i < ITEMS; i++) {
        if (f[i] >= 0) {
            int j = jb + (i >> 2) * (BLK * 4) + tid * 4 + (i & 3);
            int s = f[i] >> SEGBITS;
            int r = atomicAdd(&L.cursor[s], 1);
            L.staged[L.lstart[s] + r] = ((f[i] & (SEG - 1)) << JBITS) | j;
        }
    }
    __syncthreads();
    // copy runs: wave w handles segments w, w+4, ... (runs avg ~21 entries)
    for (int s = w; s < NSEG; s += BLK / 64) {
        int c = L.hist[s], ls = L.lstart[s], gb = L.gbase[s];
        size_t row = ((size_t)b * NSEG + s) * cap;
        for (int t = lane; t < c; t += 64)
            if (gb + t < cap) bucket[row + gb + t] = L.staged[ls + t];
    }
}

// ---------------------------------------------------------------------------
// binA: bin idx1 entries (facet f1, position g) by segment.
__global__ __launch_bounds__(BLK) void binA_kernel(
        const int* __restrict__ idx1, int* __restrict__ cnt,
        int* __restrict__ bucket, int N, int nchunk, int cap) {
    __shared__ MsLds L;
    int id = blockIdx.x;
    int xcd = id & 7, k = id >> 3;          // XCD-pin pair b (b%8==xcd)
    int b = xcd + 8 * (k / nchunk);
    int chunk = k % nchunk;
    int tid = threadIdx.x;
    int jb = chunk * CHUNKSZ;
    const int* row = idx1 + (size_t)b * N;
    int f[ITEMS];
    #pragma unroll
    for (int i4 = 0; i4 < ITEMS / 4; i4++) {
        int j0 = jb + i4 * (BLK * 4) + tid * 4;
        if (j0 + 3 < N) {
            int4 v = *reinterpret_cast<const int4*>(row + j0);
            f[i4 * 4 + 0] = v.x; f[i4 * 4 + 1] = v.y;
            f[i4 * 4 + 2] = v.z; f[i4 * 4 + 3] = v.w;
        } else {
            #pragma unroll
            for (int s = 0; s < 4; s++)
                f[i4 * 4 + s] = (j0 + s < N) ? row[j0 + s] : -1;
        }
    }
    multisplit(L, f, jb, b, cnt, bucket, cap, tid);
}

// ---------------------------------------------------------------------------
// binB: c = corr[idx0[j]]; invalid -> write out rows 0/2 now; valid -> bin.
__global__ __launch_bounds__(BLK) void binB_kernel(
        const int* __restrict__ corr, const int* __restrict__ idx0,
        int* __restrict__ cnt, int* __restrict__ bucket,
        float* __restrict__ out, int N, int nchunk, int cap) {
    __shared__ MsLds L;
    int id = blockIdx.x;
    int xcd = id & 7, k = id >> 3;
    int b = xcd + 8 * (k / nchunk);
    int chunk = k % nchunk;
    int tid = threadIdx.x;
    int jb = chunk * CHUNKSZ;
    const int* row = idx0 + (size_t)b * N;
    const int* crow = corr + (size_t)b * FCOUNT;
    size_t obase = (size_t)b * 3 * N;
    int f[ITEMS];
    #pragma unroll
    for (int i4 = 0; i4 < ITEMS / 4; i4++) {
        int j0 = jb + i4 * (BLK * 4) + tid * 4;
        int t4[4];
        if (j0 + 3 < N) {
            int4 v = *reinterpret_cast<const int4*>(row + j0);
            t4[0] = v.x; t4[1] = v.y; t4[2] = v.z; t4[3] = v.w;
        } else {
            #pragma unroll
            for (int s = 0; s < 4; s++)
                t4[s] = (j0 + s < N) ? row[j0 + s] : -1;
        }
        #pragma unroll
        for (int s = 0; s < 4; s++) {
            int fv = -1;
            if (t4[s] >= 0) {               // in-range j (idx0 values are >=0)
                int c = crow[t4[s]];
                if (c >= 0) {
                    fv = c;
                } else {
                    int j = j0 + s;
                    out[obase + j] = -1.0f;         // gt_matches0
                    out[obase + 2 * N + j] = 0.0f;  // masked score
                }
            }
            f[i4 * 4 + s] = fv;
        }
    }
    multisplit(L, f, jb, b, cnt, bucket, cap, tid);
}

// ---------------------------------------------------------------------------
// passC: per (pair, segment): build pos (inverse of idx1) and maxq
// (max j with c(j)=f) in LDS, then write the output rows.
// gt_matches1[g] = (pos[idx1[g]]==g) ? maxq[idx1[g]] : -1.
__global__ __launch_bounds__(BLK) void passC_kernel(
        const int* __restrict__ cntA, const int* __restrict__ bucketA,
        const int* __restrict__ cntB, const int* __restrict__ bucketB,
        const float* __restrict__ scores, float* __restrict__ out,
        int N, int cap) {
    __shared__ int posv[SEG];   // 16 KB
    __shared__ int maxq[SEG];   // 16 KB
    int id = blockIdx.x;
    int xcd = id & 7, k = id >> 3;
    int b = xcd + 8 * (k / NSEG);
    int s = k % NSEG;
    int tid = threadIdx.x;
    for (int t = tid; t < SEG; t += BLK) { posv[t] = -1; maxq[t] = -1; }
    __syncthreads();
    int nA = cntA[b * NSEG + s]; if (nA > cap) nA = cap;
    int nB = cntB[b * NSEG + s]; if (nB > cap) nB = cap;
    const int* bA = &bucketA[((size_t)b * NSEG + s) * cap];
    const int* bB = &bucketB[((size_t)b * NSEG + s) * cap];
    for (int i = tid; i < nA; i += BLK) {
        int e = bA[i];
        atomicMax(&posv[e >> JBITS], e & JMASK);
    }
    for (int i = tid; i < nB; i += BLK) {
        int e = bB[i];
        atomicMax(&maxq[e >> JBITS], e & JMASK);
    }
    __syncthreads();
    size_t obase = (size_t)b * 3 * N;
    for (int i = tid; i < nB; i += BLK) {
        int e = bB[i];
        int f = e >> JBITS, j = e & JMASK;
        int g = posv[f];
        out[obase + j] = (float)g;
        out[obase + 2 * N + j] = (g >= 0) ? scores[(size_t)b * N + j] : 0.0f;
    }
    for (int i = tid; i < nA; i += BLK) {
        int e = bA[i];
        int f = e >> JBITS, g = e & JMASK;
        out[obase + N + g] = (posv[f] == g) ? (float)maxq[f] : -1.0f;
    }
}

// ---------------------------------------------------------------------------
extern "C" void kernel_launch(void* const* d_in, const int* in_sizes, int n_in,
                              void* d_out, int out_size, void* d_ws, size_t ws_size,
                              hipStream_t stream) {
    const int*   corr   = (const int*)d_in[0];
    const int*   idx0   = (const int*)d_in[1];
    const int*   idx1   = (const int*)d_in[2];
    const float* scores = (const float*)d_in[3];
    float* out = (float*)d_out;

    const int B = in_sizes[0] / FCOUNT;   // 64 (multiple of 8)
    const int N = in_sizes[1] / B;        // 200000 (< 2^18)

    const int nbkt = B * NSEG;            // 12288 buckets
    int* cntA = (int*)d_ws;
    int* cntB = cntA + nbkt;
    size_t head = (size_t)2 * nbkt * sizeof(int);
    // expected bucket load ~ N/NSEG = 1042; cap from ws (>=192MB -> 2047)
    long long cap_ll = (long long)((ws_size - head) / ((size_t)2 * nbkt * sizeof(int)));
    int cap = (cap_ll > 4096) ? 4096 : (int)cap_ll;
    int* bucketA = cntB + nbkt;
    int* bucketB = bucketA + (size_t)nbkt * cap;

    hipMemsetAsync(cntA, 0, head, stream);

    int nchunk = (N + CHUNKSZ - 1) / CHUNKSZ;
    binA_kernel<<<B * nchunk, BLK, 0, stream>>>(idx1, cntA, bucketA, N, nchunk, cap);
    binB_kernel<<<B * nchunk, BLK, 0, stream>>>(corr, idx0, cntB, bucketB, out, N, nchunk, cap);
    passC_kernel<<<B * NSEG, BLK, 0, stream>>>(cntA, bucketA, cntB, bucketB,
                                               scores, out, N, cap);
}